// Round 2
// baseline (553.173 us; speedup 1.0000x reference)
//
#include <hip/hip_runtime.h>

typedef unsigned int uint;
typedef unsigned short ushort;

typedef float f32x4 __attribute__((ext_vector_type(4)));
typedef __bf16 bf16x8 __attribute__((ext_vector_type(8)));

__device__ __forceinline__ float bf2f(uint bits) {
  return __uint_as_float(bits << 16);
}
__device__ __forceinline__ ushort f2bf(float f) {
  uint u = __float_as_uint(f);
  u += 0x7fffu + ((u >> 16) & 1u);   // round-to-nearest-even
  return (ushort)(u >> 16);
}
__device__ __forceinline__ uint pack2(float a, float b) {
  return (uint)f2bf(a) | ((uint)f2bf(b) << 16);
}

// ---------- dtype probe: bf16-packed vs float32 ----------
// For bf16 pairs, low 16 bits of each u32 is a bf16 whose exp in [116,130]
// for ~all N(0,1) draws. For f32, low 16 bits are uniform mantissa bits
// (~6% in range). 64-sample vote is decisive.
__global__ void detect_k(const uint* __restrict__ xu, int* __restrict__ flag) {
  uint u = xu[threadIdx.x];
  uint e = (u >> 7) & 0xFFu;
  unsigned long long m = __ballot(e >= 116u && e <= 130u);
  if (threadIdx.x == 0) flag[0] = (__builtin_popcountll(m) >= 32) ? 1 : 0;
}

// ---------- CSR build ----------
__global__ void count_deg(const int* __restrict__ src, const int* __restrict__ dst,
                          int* __restrict__ deg_out, int* __restrict__ deg_in, int E) {
  int e = blockIdx.x * blockDim.x + threadIdx.x;
  if (e < E) {
    atomicAdd(&deg_out[src[e]], 1);
    atomicAdd(&deg_in[dst[e]], 1);
  }
}

__global__ void norms_k(const int* __restrict__ deg_out, const int* __restrict__ deg_in,
                        float* __restrict__ ns, float* __restrict__ nd, int n) {
  int i = blockIdx.x * blockDim.x + threadIdx.x;
  if (i < n) {
    ns[i] = rsqrtf(fmaxf((float)deg_out[i], 1.f));
    nd[i] = rsqrtf(fmaxf((float)deg_in[i], 1.f));
  }
}

__global__ void scan1(const int* __restrict__ deg, int* __restrict__ tmp,
                      int* __restrict__ bsums, int n) {
  __shared__ int lds[256];
  int tid = threadIdx.x;
  int idx = blockIdx.x * 1024 + tid * 4;
  int v[4];
  int s = 0;
#pragma unroll
  for (int j = 0; j < 4; ++j) {
    v[j] = (idx + j < n) ? deg[idx + j] : 0;
    s += v[j];
  }
  lds[tid] = s;
  __syncthreads();
  for (int off = 1; off < 256; off <<= 1) {
    int t_ = 0;
    if (tid >= off) t_ = lds[tid - off];
    __syncthreads();
    if (tid >= off) lds[tid] += t_;
    __syncthreads();
  }
  int run = (tid > 0) ? lds[tid - 1] : 0;
#pragma unroll
  for (int j = 0; j < 4; ++j) {
    run += v[j];
    if (idx + j < n) tmp[idx + j] = run;
  }
  if (tid == 255) bsums[blockIdx.x] = lds[255];
}

__global__ void scan2(int* __restrict__ bsums, int nb) {
  if (blockIdx.x == 0 && threadIdx.x == 0) {
    int run = 0;
    for (int i = 0; i < nb; ++i) { int v = bsums[i]; bsums[i] = run; run += v; }
  }
}

__global__ void scan3(const int* __restrict__ tmp, const int* __restrict__ bsums,
                      int* __restrict__ row_off, int n) {
  int i = blockIdx.x * blockDim.x + threadIdx.x;
  if (i < n) row_off[i + 1] = tmp[i] + bsums[i >> 10];
  if (i == 0) row_off[0] = 0;
}

__global__ void bucket_k(const int* __restrict__ src, const int* __restrict__ dst,
                         const int* __restrict__ row_off, int* __restrict__ cursor,
                         int* __restrict__ csr, int E) {
  int e = blockIdx.x * blockDim.x + threadIdx.x;
  if (e < E) {
    int d = dst[e];
    int r = atomicAdd(&cursor[d], 1);
    csr[row_off[d] + r] = src[e];
  }
}

// ---------- W fragment pre-swizzle (B-operand layout, 16x16x32 bf16) ----------
__global__ void wswz(const void* __restrict__ W1p, const void* __restrict__ W2p,
                     ushort* __restrict__ wf1, ushort* __restrict__ wf2,
                     const int* __restrict__ flagp) {
  int bf = *flagp;
  int tid = blockIdx.x * blockDim.x + threadIdx.x;  // 0..4095
  const void* W = (tid & 2048) ? W2p : W1p;
  ushort* wf = (tid & 2048) ? wf2 : wf1;
  int chunk = tid & 2047;
  int n0 = chunk & 15;
  int quad = (chunk >> 4) & 3;
  int kk = (chunk >> 6) & 3;
  int c = chunk >> 8;
  int col = c * 16 + n0;
#pragma unroll
  for (int j = 0; j < 8; ++j) {
    int idx = (kk * 32 + quad * 8 + j) * 128 + col;
    ushort v = bf ? ((const ushort*)W)[idx] : f2bf(((const float*)W)[idx]);
    wf[chunk * 8 + j] = v;
  }
}

// ---------- GEMM: t[r][:] = (x[r][:] @ W) * ns[r] ----------
__global__ __launch_bounds__(256) void gemm_ns(const void* __restrict__ xp,
                                               const ushort* __restrict__ wf,
                                               const float* __restrict__ ns,
                                               ushort* __restrict__ t,
                                               const int* __restrict__ flagp,
                                               int forced_bf, int n) {
  __shared__ __align__(16) ushort Xs[64][136];
  __shared__ __align__(16) ushort Ws[16384];
  const int tid = threadIdx.x;
  const int rowbase = blockIdx.x * 64;
  const int eff_bf = forced_bf | *flagp;

#pragma unroll
  for (int i = 0; i < 8; ++i)
    ((uint4*)Ws)[i * 256 + tid] = ((const uint4*)wf)[i * 256 + tid];

#pragma unroll
  for (int i = 0; i < 4; ++i) {
    int cid = i * 256 + tid;       // 1024 chunks of 8 elements
    int r = cid >> 4;
    int co = (cid & 15) << 3;
    int gr = rowbase + r;
    uint4 v = {0u, 0u, 0u, 0u};
    if (gr < n) {
      if (eff_bf) {
        v = *(const uint4*)((const ushort*)xp + (size_t)gr * 128 + co);
      } else {
        const float* xf = (const float*)xp + (size_t)gr * 128 + co;
        float4 f0 = *(const float4*)xf;
        float4 f1 = *(const float4*)(xf + 4);
        v.x = pack2(f0.x, f0.y); v.y = pack2(f0.z, f0.w);
        v.z = pack2(f1.x, f1.y); v.w = pack2(f1.z, f1.w);
      }
    }
    *(uint4*)&Xs[r][co] = v;
  }
  __syncthreads();

  const int w = tid >> 6;
  const int lane = tid & 63;
  const int m = lane & 15;
  const int quad = lane >> 4;

  bf16x8 a[4];
#pragma unroll
  for (int kk = 0; kk < 4; ++kk)
    a[kk] = *(const bf16x8*)&Xs[w * 16 + m][kk * 32 + quad * 8];

  int grs[4];
  float nsv[4];
#pragma unroll
  for (int reg = 0; reg < 4; ++reg) {
    int gr = rowbase + w * 16 + quad * 4 + reg;
    grs[reg] = gr;
    nsv[reg] = (gr < n) ? ns[gr] : 0.f;
  }

#pragma unroll
  for (int c = 0; c < 8; ++c) {
    f32x4 acc = {0.f, 0.f, 0.f, 0.f};
#pragma unroll
    for (int kk = 0; kk < 4; ++kk) {
      bf16x8 b = *(const bf16x8*)&Ws[(((c * 4 + kk) * 4 + quad) * 16 + m) * 8];
      acc = __builtin_amdgcn_mfma_f32_16x16x32_bf16(a[kk], b, acc, 0, 0, 0);
    }
    int col = c * 16 + m;
#pragma unroll
    for (int reg = 0; reg < 4; ++reg) {
      if (grs[reg] < n)
        t[(size_t)grs[reg] * 128 + col] = f2bf(acc[reg] * nsv[reg]);
    }
  }
}

// ---------- aggregation ----------
__global__ __launch_bounds__(256) void agg_k(const uint* __restrict__ tu,
                                             const int* __restrict__ row_off,
                                             const int* __restrict__ csr,
                                             const float* __restrict__ nd,
                                             const void* __restrict__ bp,
                                             void* __restrict__ outp,
                                             int relu, int is_final,
                                             const int* __restrict__ flagp, int n) {
  int node = (blockIdx.x * 256 + threadIdx.x) >> 6;  // one wave per node
  int lane = threadIdx.x & 63;
  int bf = *flagp;
  if (node >= n) return;
  int e0 = row_off[node], e1 = row_off[node + 1];
  float a0 = 0.f, a1 = 0.f;
  int e = e0;
  for (; e + 4 <= e1; e += 4) {
    int s0 = csr[e], s1 = csr[e + 1], s2 = csr[e + 2], s3 = csr[e + 3];
    uint v0 = tu[(size_t)s0 * 64 + lane];
    uint v1 = tu[(size_t)s1 * 64 + lane];
    uint v2 = tu[(size_t)s2 * 64 + lane];
    uint v3 = tu[(size_t)s3 * 64 + lane];
    a0 += (bf2f(v0 & 0xffffu) + bf2f(v1 & 0xffffu)) + (bf2f(v2 & 0xffffu) + bf2f(v3 & 0xffffu));
    a1 += (bf2f(v0 >> 16) + bf2f(v1 >> 16)) + (bf2f(v2 >> 16) + bf2f(v3 >> 16));
  }
  for (; e < e1; ++e) {
    int s = csr[e];
    uint v = tu[(size_t)s * 64 + lane];
    a0 += bf2f(v & 0xffffu);
    a1 += bf2f(v >> 16);
  }
  float bias0, bias1;
  if (bf) {
    uint bv = ((const uint*)bp)[lane];
    bias0 = bf2f(bv & 0xffffu);
    bias1 = bf2f(bv >> 16);
  } else {
    const float* b32 = (const float*)bp;
    bias0 = b32[2 * lane];
    bias1 = b32[2 * lane + 1];
  }
  float nrm = nd[node];
  float o0 = a0 * nrm + bias0;
  float o1 = a1 * nrm + bias1;
  if (relu) { o0 = fmaxf(o0, 0.f); o1 = fmaxf(o1, 0.f); }
  if (!is_final || bf) {
    ((uint*)outp)[(size_t)node * 64 + lane] = pack2(o0, o1);
  } else {
    ((float2*)outp)[(size_t)node * 64 + lane] = make_float2(o0, o1);
  }
}

extern "C" void kernel_launch(void* const* d_in, const int* in_sizes, int n_in,
                              void* d_out, int out_size, void* d_ws, size_t ws_size,
                              hipStream_t stream) {
  const int n = in_sizes[0] / 128;   // 100000 nodes
  const int E = in_sizes[1];         // 1600000 edges

  const void* feat = d_in[0];
  const int* src = (const int*)d_in[1];
  const int* dst = (const int*)d_in[2];
  const void* W1 = d_in[3];
  const void* b1 = d_in[4];
  const void* W2 = d_in[5];
  const void* b2 = d_in[6];

  // workspace carve-up (256B-aligned slabs); ~35 MB total
  char* p = (char*)d_ws;
  auto alloc = [&](size_t bytes) -> char* {
    char* q = p;
    p += (bytes + 255) & ~(size_t)255;
    return q;
  };
  int* flag = (int*)alloc(256);
  ushort* t = (ushort*)alloc((size_t)n * 128 * 2);   // GEMM output (internal bf16)
  ushort* wf1 = (ushort*)alloc(16384 * 2);
  ushort* wf2 = (ushort*)alloc(16384 * 2);
  int* deg_out = (int*)alloc((size_t)3 * n * 4);     // deg_out | deg_in | cursor
  int* deg_in = deg_out + n;
  int* cursor = deg_out + 2 * n;
  float* ns = (float*)alloc((size_t)n * 4);
  float* nd = (float*)alloc((size_t)n * 4);
  int* tmp = (int*)alloc((size_t)n * 4);
  int* bsums = (int*)alloc(256 * 4);
  int* row_off = (int*)alloc((size_t)(n + 1) * 4);
  int* csr = (int*)alloc((size_t)E * 4);

  // layer-1 intermediate lives in d_out (internal bf16), overwritten by final
  ushort* y1 = (ushort*)d_out;

  const int TB = 256;
  const int gE = (E + TB - 1) / TB;
  const int gN = (n + TB - 1) / TB;
  const int nb = (n + 1023) / 1024;
  const int gGemm = (n + 63) / 64;
  const int gAgg = (n + 3) / 4;

  detect_k<<<1, 64, 0, stream>>>((const uint*)feat, flag);
  hipMemsetAsync(deg_out, 0, (size_t)3 * n * 4, stream);
  count_deg<<<gE, TB, 0, stream>>>(src, dst, deg_out, deg_in, E);
  norms_k<<<gN, TB, 0, stream>>>(deg_out, deg_in, ns, nd, n);
  scan1<<<nb, TB, 0, stream>>>(deg_in, tmp, bsums, n);
  scan2<<<1, 64, 0, stream>>>(bsums, nb);
  scan3<<<gN, TB, 0, stream>>>(tmp, bsums, row_off, n);
  bucket_k<<<gE, TB, 0, stream>>>(src, dst, row_off, cursor, csr, E);
  wswz<<<16, TB, 0, stream>>>(W1, W2, wf1, wf2, flag);

  // layer 1
  gemm_ns<<<gGemm, TB, 0, stream>>>(feat, wf1, ns, t, flag, 0, n);
  agg_k<<<gAgg, TB, 0, stream>>>((const uint*)t, row_off, csr, nd, b1,
                                 (void*)y1, 1, 0, flag, n);
  // layer 2 (y1 is internal bf16 regardless of input dtype)
  gemm_ns<<<gGemm, TB, 0, stream>>>((const void*)y1, wf2, ns, t, flag, 1, n);
  agg_k<<<gAgg, TB, 0, stream>>>((const uint*)t, row_off, csr, nd, b2,
                                 d_out, 0, 1, flag, n);
}